// Round 1
// baseline (741.538 us; speedup 1.0000x reference)
//
#include <hip/hip_runtime.h>
#include <hip/hip_bf16.h>
#include <math.h>

#define N_NODES 50000
#define N_EDGES 800000
#define IN_NODE 256
#define IN_EDGE 64
#define OUT_DIM 128

// ---------------------------------------------------------------------------
// K1: z = feats_node @ Wn^T  (50000x256 @ 256x128), fp32 accum.
//     Outputs: zb (bf16 copy of z, used only for message aggregation),
//              s_src[n] = Wa[0:128] . z[n],  s_dst[n] = Wa[128:256] . z[n]
// Tile: 64 nodes x 128 outs per block, K-tiles of 32. 256 threads.
// ---------------------------------------------------------------------------
#define K1_MT 64
#define K1_KT 32

__global__ __launch_bounds__(256) void k1_node_gemm(
    const float* __restrict__ fn, const float* __restrict__ Wn,
    const float* __restrict__ Wa,
    __hip_bfloat16* __restrict__ zb,
    float* __restrict__ s_src, float* __restrict__ s_dst)
{
    __shared__ float A_s[K1_KT][K1_MT + 4];    // [k][node]
    __shared__ float B_s[K1_KT][OUT_DIM + 4];  // [k][c]
    __shared__ float red_s[K1_MT][17];
    __shared__ float red_d[K1_MT][17];

    const int t  = threadIdx.x;
    const int m0 = blockIdx.x * K1_MT;
    const int tn = t & 15;        // 0..15 -> out cols
    const int tm = t >> 4;        // 0..15 -> node rows
    const int r0 = tm * 4;
    const int c0 = tn * 8;

    float acc[4][8];
    for (int i = 0; i < 4; ++i)
        for (int j = 0; j < 8; ++j) acc[i][j] = 0.f;

    for (int k0 = 0; k0 < IN_NODE; k0 += K1_KT) {
        // --- load A tile (64 nodes x 32 k), transposed into [k][node]
        {
            const int chunk = t & 7;   // k-group of 4
            const int nd    = t >> 3;  // 0..31
            for (int hh = 0; hh < 2; ++hh) {
                const int node = nd + hh * 32;
                int gr = m0 + node; if (gr >= N_NODES) gr = N_NODES - 1;
                const float4 v = *(const float4*)&fn[(size_t)gr * IN_NODE + k0 + chunk * 4];
                A_s[chunk * 4 + 0][node] = v.x;
                A_s[chunk * 4 + 1][node] = v.y;
                A_s[chunk * 4 + 2][node] = v.z;
                A_s[chunk * 4 + 3][node] = v.w;
            }
        }
        // --- load B tile (128 c x 32 k), transposed into [k][c]
        {
            const int chunk = t & 7;
            const int cb    = t >> 3;  // 0..31
            for (int hh = 0; hh < 4; ++hh) {
                const int c = cb + hh * 32;
                const float4 v = *(const float4*)&Wn[(size_t)c * IN_NODE + k0 + chunk * 4];
                B_s[chunk * 4 + 0][c] = v.x;
                B_s[chunk * 4 + 1][c] = v.y;
                B_s[chunk * 4 + 2][c] = v.z;
                B_s[chunk * 4 + 3][c] = v.w;
            }
        }
        __syncthreads();

        for (int k = 0; k < K1_KT; ++k) {
            const float4 a  = *(const float4*)&A_s[k][r0];
            const float4 b0 = *(const float4*)&B_s[k][c0];
            const float4 b1 = *(const float4*)&B_s[k][c0 + 4];
            const float av[4] = {a.x, a.y, a.z, a.w};
            const float bv[8] = {b0.x, b0.y, b0.z, b0.w, b1.x, b1.y, b1.z, b1.w};
            for (int i = 0; i < 4; ++i)
                for (int j = 0; j < 8; ++j)
                    acc[i][j] += av[i] * bv[j];
        }
        __syncthreads();
    }

    // --- attention partials from fp32 accumulators
    float wa_s[8], wa_d[8];
    for (int j = 0; j < 8; ++j) {
        wa_s[j] = Wa[c0 + j];
        wa_d[j] = Wa[OUT_DIM + c0 + j];
    }
    float ps[4], pd[4];
    for (int i = 0; i < 4; ++i) {
        float a = 0.f, b = 0.f;
        for (int j = 0; j < 8; ++j) {
            a += wa_s[j] * acc[i][j];
            b += wa_d[j] * acc[i][j];
        }
        ps[i] = a; pd[i] = b;
    }

    // --- store z as bf16 (message values only)
    for (int i = 0; i < 4; ++i) {
        const int node = m0 + r0 + i;
        if (node < N_NODES) {
            alignas(16) __hip_bfloat16 tmp[8];
            for (int j = 0; j < 8; ++j) tmp[j] = __float2bfloat16(acc[i][j]);
            *(uint4*)&zb[(size_t)node * OUT_DIM + c0] = *(const uint4*)tmp;
        }
    }

    // --- reduce s_src/s_dst across the 16 col-threads
    for (int i = 0; i < 4; ++i) {
        red_s[r0 + i][tn] = ps[i];
        red_d[r0 + i][tn] = pd[i];
    }
    __syncthreads();
    if (t < K1_MT) {
        const int node = m0 + t;
        if (node < N_NODES) {
            float a = 0.f, b = 0.f;
            for (int j = 0; j < 16; ++j) { a += red_s[t][j]; b += red_d[t][j]; }
            s_src[node] = a;
            s_dst[node] = b;
        }
    }
}

// ---------------------------------------------------------------------------
// K2: ze = feats_edge @ We^T (800000x64 @ 64x64) -> d_out (fp32), plus
//     s_e[e] = Wa[256:320] . ze[e]   fused in the epilogue.
// Tile: 64 edges x 64 outs, full K=64. 256 threads. 12500 blocks exactly.
// ---------------------------------------------------------------------------
__global__ __launch_bounds__(256) void k2_edge_gemm(
    const float* __restrict__ fe, const float* __restrict__ We,
    const float* __restrict__ Wa,
    float* __restrict__ ze_out, float* __restrict__ s_e)
{
    __shared__ float A_s[IN_EDGE][64 + 4];  // [k][edge]
    __shared__ float B_s[IN_EDGE][64 + 4];  // [k][c]
    __shared__ float red[64][17];

    const int t  = threadIdx.x;
    const size_t e0 = (size_t)blockIdx.x * 64;

    // load A (64 edges x 64 k)
    {
        const int chunk = t & 15;   // k-group of 4
        const int eb    = t >> 4;   // 0..15
        for (int hh = 0; hh < 4; ++hh) {
            const int ed = eb + hh * 16;
            const float4 v = *(const float4*)&fe[(e0 + ed) * IN_EDGE + chunk * 4];
            A_s[chunk * 4 + 0][ed] = v.x;
            A_s[chunk * 4 + 1][ed] = v.y;
            A_s[chunk * 4 + 2][ed] = v.z;
            A_s[chunk * 4 + 3][ed] = v.w;
        }
    }
    // load B (We: 64 c x 64 k)
    {
        const int chunk = t & 15;
        const int cb    = t >> 4;
        for (int hh = 0; hh < 4; ++hh) {
            const int c = cb + hh * 16;
            const float4 v = *(const float4*)&We[(size_t)c * IN_EDGE + chunk * 4];
            B_s[chunk * 4 + 0][c] = v.x;
            B_s[chunk * 4 + 1][c] = v.y;
            B_s[chunk * 4 + 2][c] = v.z;
            B_s[chunk * 4 + 3][c] = v.w;
        }
    }
    __syncthreads();

    const int tn = t & 15, tm = t >> 4;
    const int r0 = tm * 4, c0 = tn * 4;
    float acc[4][4];
    for (int i = 0; i < 4; ++i)
        for (int j = 0; j < 4; ++j) acc[i][j] = 0.f;

    for (int k = 0; k < IN_EDGE; ++k) {
        const float4 a = *(const float4*)&A_s[k][r0];
        const float4 b = *(const float4*)&B_s[k][c0];
        const float av[4] = {a.x, a.y, a.z, a.w};
        const float bv[4] = {b.x, b.y, b.z, b.w};
        for (int i = 0; i < 4; ++i)
            for (int j = 0; j < 4; ++j)
                acc[i][j] += av[i] * bv[j];
    }

    // write ze
    for (int i = 0; i < 4; ++i) {
        float4 v = make_float4(acc[i][0], acc[i][1], acc[i][2], acc[i][3]);
        *(float4*)&ze_out[(e0 + r0 + i) * IN_EDGE + c0] = v;
    }

    // fused s_e
    float wa[4];
    for (int j = 0; j < 4; ++j) wa[j] = Wa[2 * OUT_DIM + c0 + j];
    for (int i = 0; i < 4; ++i) {
        float pv = 0.f;
        for (int j = 0; j < 4; ++j) pv += wa[j] * acc[i][j];
        red[r0 + i][tn] = pv;
    }
    __syncthreads();
    if (t < 64) {
        float sum = 0.f;
        for (int j = 0; j < 16; ++j) sum += red[t][j];
        s_e[e0 + t] = sum;
    }
}

// ---------------------------------------------------------------------------
// CSR construction
// ---------------------------------------------------------------------------
__global__ void k3_degree(const int* __restrict__ dst, int* __restrict__ deg)
{
    const int i = blockIdx.x * blockDim.x + threadIdx.x;
    if (i < N_EDGES) atomicAdd(&deg[dst[i]], 1);
}

#define SCAN_T 1024
#define SCAN_C 49

__global__ __launch_bounds__(SCAN_T) void k4_scan(
    const int* __restrict__ deg, int* __restrict__ off, int* __restrict__ cursor)
{
    __shared__ int part[SCAN_T];
    const int t = threadIdx.x;
    const int lo = t * SCAN_C;
    int hi = lo + SCAN_C; if (hi > N_NODES) hi = N_NODES;

    int s = 0;
    for (int i = lo; i < hi; ++i) s += deg[i];
    part[t] = s;
    __syncthreads();
    for (int d = 1; d < SCAN_T; d <<= 1) {
        int v = 0;
        if (t >= d) v = part[t - d];
        __syncthreads();
        if (t >= d) part[t] += v;
        __syncthreads();
    }
    int run = (t == 0) ? 0 : part[t - 1];
    for (int i = lo; i < hi; ++i) {
        off[i] = run; cursor[i] = run;
        run += deg[i];
    }
    if (t == SCAN_T - 1) off[N_NODES] = part[SCAN_T - 1];
}

__global__ void k5_fill(
    const int* __restrict__ src, const int* __restrict__ dst,
    const float* __restrict__ s_src, const float* __restrict__ s_dst,
    const float* __restrict__ s_e, int* __restrict__ cursor,
    int* __restrict__ csr_src, float* __restrict__ csr_e)
{
    const int i = blockIdx.x * blockDim.x + threadIdx.x;
    if (i >= N_EDGES) return;
    const int d = dst[i];
    const int s = src[i];
    const int pos = atomicAdd(&cursor[d], 1);
    csr_src[pos] = s;
    float e = s_src[s] + s_dst[d] + s_e[i];
    e = (e > 0.f) ? e : 0.2f * e;
    csr_e[pos] = e;
}

// ---------------------------------------------------------------------------
// K6: one wave per dst node: segment max -> exp-sum + weighted message
//     aggregation (bf16 z gather, fp32 accumulate). Fully deterministic
//     per-node output, deg==0 writes zeros (matches segment_sum).
// ---------------------------------------------------------------------------
__global__ __launch_bounds__(256) void k6_aggregate(
    const int* __restrict__ off, const int* __restrict__ csr_src,
    const float* __restrict__ csr_e, const __hip_bfloat16* __restrict__ zb,
    float* __restrict__ h)
{
    const int wave = (int)((blockIdx.x * blockDim.x + threadIdx.x) >> 6);
    const int lane = threadIdx.x & 63;
    if (wave >= N_NODES) return;

    const int beg = off[wave];
    const int end = off[wave + 1];
    const int deg = end - beg;

    float2 acc = make_float2(0.f, 0.f);
    if (deg > 0) {
        float m = -INFINITY;
        for (int j = lane; j < deg; j += 64) m = fmaxf(m, csr_e[beg + j]);
        for (int o = 32; o > 0; o >>= 1) m = fmaxf(m, __shfl_xor(m, o, 64));

        float l = 0.f;
        for (int j = 0; j < deg; ++j) {
            const int s = csr_src[beg + j];
            const float w = __expf(csr_e[beg + j] - m);
            l += w;
            const __hip_bfloat162 zp =
                *(const __hip_bfloat162*)&zb[(size_t)s * OUT_DIM + lane * 2];
            const float2 zv = __bfloat1622float2(zp);
            acc.x += w * zv.x;
            acc.y += w * zv.y;
        }
        const float inv = 1.f / fmaxf(l, 1e-38f);
        acc.x *= inv; acc.y *= inv;
    }
    *(float2*)&h[(size_t)wave * OUT_DIM + lane * 2] = acc;
}

// ---------------------------------------------------------------------------
extern "C" void kernel_launch(void* const* d_in, const int* in_sizes, int n_in,
                              void* d_out, int out_size, void* d_ws, size_t ws_size,
                              hipStream_t stream)
{
    const float* fn  = (const float*)d_in[0];
    const float* fe  = (const float*)d_in[1];
    const int*   src = (const int*)d_in[2];
    const int*   dst = (const int*)d_in[3];
    const float* Wn  = (const float*)d_in[4];
    const float* We  = (const float*)d_in[5];
    const float* Wa  = (const float*)d_in[6];

    float* h_out  = (float*)d_out;                          // [50000,128]
    float* ze_out = h_out + (size_t)N_NODES * OUT_DIM;      // [800000,64]

    char* p = (char*)d_ws;
    auto alloc = [&](size_t bytes) -> char* {
        char* r = p;
        p += (bytes + 255) & ~(size_t)255;
        return r;
    };
    __hip_bfloat16* zb   = (__hip_bfloat16*)alloc((size_t)N_NODES * OUT_DIM * 2);
    float* s_src   = (float*)alloc((size_t)N_NODES * 4);
    float* s_dst   = (float*)alloc((size_t)N_NODES * 4);
    float* s_e     = (float*)alloc((size_t)N_EDGES * 4);
    int*   deg     = (int*)alloc((size_t)N_NODES * 4);
    int*   off     = (int*)alloc((size_t)(N_NODES + 1) * 4);
    int*   cursor  = (int*)alloc((size_t)N_NODES * 4);
    int*   csr_src = (int*)alloc((size_t)N_EDGES * 4);
    float* csr_e   = (float*)alloc((size_t)N_EDGES * 4);

    hipMemsetAsync(deg, 0, (size_t)N_NODES * sizeof(int), stream);

    k1_node_gemm<<<(N_NODES + K1_MT - 1) / K1_MT, 256, 0, stream>>>(
        fn, Wn, Wa, zb, s_src, s_dst);
    k2_edge_gemm<<<N_EDGES / 64, 256, 0, stream>>>(fe, We, Wa, ze_out, s_e);
    k3_degree<<<(N_EDGES + 255) / 256, 256, 0, stream>>>(dst, deg);
    k4_scan<<<1, SCAN_T, 0, stream>>>(deg, off, cursor);
    k5_fill<<<(N_EDGES + 255) / 256, 256, 0, stream>>>(
        src, dst, s_src, s_dst, s_e, cursor, csr_src, csr_e);
    k6_aggregate<<<(N_NODES + 3) / 4, 256, 0, stream>>>(
        off, csr_src, csr_e, zb, h_out);
}

// Round 3
// 711.074 us; speedup vs baseline: 1.0428x; 1.0428x over previous
//
#include <hip/hip_runtime.h>
#include <hip/hip_bf16.h>
#include <math.h>

#define N_NODES 50000
#define N_EDGES 800000
#define IN_NODE 256
#define IN_EDGE 64
#define OUT_DIM 128

typedef __attribute__((ext_vector_type(8))) short short8;   // 8 bf16 (4 VGPR)
typedef __attribute__((ext_vector_type(4))) float f32x4;    // MFMA accum

__device__ inline short f2bf(float x) {   // RNE float->bf16 (no NaN inputs here)
    union { float f; unsigned u; } v; v.f = x;
    unsigned r = v.u + 0x7fff + ((v.u >> 16) & 1);
    return (short)(r >> 16);
}

__device__ inline void cvt_store8(short* p, float4 a, float4 b) {
    union { short h[8]; uint4 u; } t;
    t.h[0] = f2bf(a.x); t.h[1] = f2bf(a.y); t.h[2] = f2bf(a.z); t.h[3] = f2bf(a.w);
    t.h[4] = f2bf(b.x); t.h[5] = f2bf(b.y); t.h[6] = f2bf(b.z); t.h[7] = f2bf(b.w);
    *(uint4*)p = t.u;
}

// ---------------------------------------------------------------------------
// K0: v_e = We^T @ Wa_edge  (64 floats) — so s_e can be computed from fp32 fe
//     directly: s_e[e] = fe[e] . v_e  (exact fp32 logit path).
// ---------------------------------------------------------------------------
__global__ void k0_ve(const float* __restrict__ We, const float* __restrict__ Wa,
                      float* __restrict__ v_e)
{
    const int k = threadIdx.x;
    if (k < IN_EDGE) {
        float s = 0.f;
        for (int c = 0; c < IN_EDGE; ++c)
            s += We[c * IN_EDGE + k] * Wa[2 * OUT_DIM + c];
        v_e[k] = s;
    }
}

// ---------------------------------------------------------------------------
// K1: z = feats_node @ Wn^T  (50000x256 @ 256x128), fp32 accum.
//     Outputs: zb (bf16 z, message values), s_src/s_dst (fp32 logit partials).
// ---------------------------------------------------------------------------
#define K1_MT 64
#define K1_KT 32

__global__ __launch_bounds__(256) void k1_node_gemm(
    const float* __restrict__ fn, const float* __restrict__ Wn,
    const float* __restrict__ Wa,
    __hip_bfloat16* __restrict__ zb,
    float* __restrict__ s_src, float* __restrict__ s_dst)
{
    __shared__ float A_s[K1_KT][K1_MT + 4];    // [k][node]
    __shared__ float B_s[K1_KT][OUT_DIM + 4];  // [k][c]
    __shared__ float red_s[K1_MT][17];
    __shared__ float red_d[K1_MT][17];

    const int t  = threadIdx.x;
    const int m0 = blockIdx.x * K1_MT;
    const int tn = t & 15;
    const int tm = t >> 4;
    const int r0 = tm * 4;
    const int c0 = tn * 8;

    float acc[4][8];
    for (int i = 0; i < 4; ++i)
        for (int j = 0; j < 8; ++j) acc[i][j] = 0.f;

    for (int k0 = 0; k0 < IN_NODE; k0 += K1_KT) {
        {
            const int chunk = t & 7;
            const int nd    = t >> 3;
            for (int hh = 0; hh < 2; ++hh) {
                const int node = nd + hh * 32;
                int gr = m0 + node; if (gr >= N_NODES) gr = N_NODES - 1;
                const float4 v = *(const float4*)&fn[(size_t)gr * IN_NODE + k0 + chunk * 4];
                A_s[chunk * 4 + 0][node] = v.x;
                A_s[chunk * 4 + 1][node] = v.y;
                A_s[chunk * 4 + 2][node] = v.z;
                A_s[chunk * 4 + 3][node] = v.w;
            }
        }
        {
            const int chunk = t & 7;
            const int cb    = t >> 3;
            for (int hh = 0; hh < 4; ++hh) {
                const int c = cb + hh * 32;
                const float4 v = *(const float4*)&Wn[(size_t)c * IN_NODE + k0 + chunk * 4];
                B_s[chunk * 4 + 0][c] = v.x;
                B_s[chunk * 4 + 1][c] = v.y;
                B_s[chunk * 4 + 2][c] = v.z;
                B_s[chunk * 4 + 3][c] = v.w;
            }
        }
        __syncthreads();

        for (int k = 0; k < K1_KT; ++k) {
            const float4 a  = *(const float4*)&A_s[k][r0];
            const float4 b0 = *(const float4*)&B_s[k][c0];
            const float4 b1 = *(const float4*)&B_s[k][c0 + 4];
            const float av[4] = {a.x, a.y, a.z, a.w};
            const float bv[8] = {b0.x, b0.y, b0.z, b0.w, b1.x, b1.y, b1.z, b1.w};
            for (int i = 0; i < 4; ++i)
                for (int j = 0; j < 8; ++j)
                    acc[i][j] += av[i] * bv[j];
        }
        __syncthreads();
    }

    float wa_s[8], wa_d[8];
    for (int j = 0; j < 8; ++j) {
        wa_s[j] = Wa[c0 + j];
        wa_d[j] = Wa[OUT_DIM + c0 + j];
    }
    float ps[4], pd[4];
    for (int i = 0; i < 4; ++i) {
        float a = 0.f, b = 0.f;
        for (int j = 0; j < 8; ++j) {
            a += wa_s[j] * acc[i][j];
            b += wa_d[j] * acc[i][j];
        }
        ps[i] = a; pd[i] = b;
    }

    for (int i = 0; i < 4; ++i) {
        const int node = m0 + r0 + i;
        if (node < N_NODES) {
            alignas(16) __hip_bfloat16 tmp[8];
            for (int j = 0; j < 8; ++j) tmp[j] = __float2bfloat16(acc[i][j]);
            *(uint4*)&zb[(size_t)node * OUT_DIM + c0] = *(const uint4*)tmp;
        }
    }

    for (int i = 0; i < 4; ++i) {
        red_s[r0 + i][tn] = ps[i];
        red_d[r0 + i][tn] = pd[i];
    }
    __syncthreads();
    if (t < K1_MT) {
        const int node = m0 + t;
        if (node < N_NODES) {
            float a = 0.f, b = 0.f;
            for (int j = 0; j < 16; ++j) { a += red_s[t][j]; b += red_d[t][j]; }
            s_src[node] = a;
            s_dst[node] = b;
        }
    }
}

// ---------------------------------------------------------------------------
// K2 (MFMA): ze = feats_edge @ We^T  via bf16 16x16x32 MFMA (ze output only —
//   bf16 rounding stays within output-1's threshold).
//   s_e is computed IN FP32 during staging from the exact fe values:
//   s_e[e] = fe[e].v_e  — the logit path never sees bf16.
//   Fused: degree-count atomics (old k3).
// ---------------------------------------------------------------------------
__global__ __launch_bounds__(256) void k2_edge_gemm_mfma(
    const float* __restrict__ fe, const float* __restrict__ We,
    const float* __restrict__ v_e,
    const int* __restrict__ dst, int* __restrict__ deg,
    float* __restrict__ ze_out, float* __restrict__ s_e)
{
    __shared__ alignas(16) short A_lds[128][72];  // [edge][k] bf16, +8 pad
    __shared__ alignas(16) short B_lds[64][72];   // [col][k]  bf16, +8 pad

    const int t    = threadIdx.x;
    const int lane = t & 63;
    const int w    = t >> 6;          // wave 0..3
    const long e0  = (long)blockIdx.x * 128;

    // fused degree count (old k3)
    if (t < 128) atomicAdd(&deg[dst[e0 + t]], 1);

    // --- stage A: fe[e0..e0+127][0..63] -> bf16 LDS, plus fp32 s_e partial
    {
        const int edge = t >> 1, half = t & 1;
        const float4* rp = (const float4*)&fe[(e0 + edge) * IN_EDGE + half * 32];
        float4 va[8];
        for (int q = 0; q < 8; ++q) va[q] = rp[q];

        float part = 0.f;
        for (int q = 0; q < 8; ++q) {
            const float4 w4 = *(const float4*)&v_e[half * 32 + q * 4];
            part += va[q].x * w4.x + va[q].y * w4.y
                  + va[q].z * w4.z + va[q].w * w4.w;
        }
        const float other = __shfl_xor(part, 1, 64);
        if (half == 0) s_e[e0 + edge] = part + other;

        short* wp = &A_lds[edge][half * 32];
        for (int q = 0; q < 4; ++q)
            cvt_store8(wp + q * 8, va[2 * q], va[2 * q + 1]);
    }
    // --- stage B: We[c][k] -> bf16 LDS
    {
        const int row = t >> 2, kq = (t & 3) * 16;
        const float4* rp = (const float4*)&We[(size_t)row * IN_EDGE + kq];
        cvt_store8(&B_lds[row][kq + 0], rp[0], rp[1]);
        cvt_store8(&B_lds[row][kq + 8], rp[2], rp[3]);
    }
    __syncthreads();

    const int lrow = lane & 15;        // A row / B col within 16-tile
    const int lk   = (lane >> 4) * 8;  // k offset within 32-k step

    f32x4 acc[2][4];
    for (int r = 0; r < 2; ++r)
        for (int c = 0; c < 4; ++c)
            acc[r][c] = (f32x4){0.f, 0.f, 0.f, 0.f};

    for (int s = 0; s < 2; ++s) {      // two 32-k steps
        const int kk = s * 32 + lk;
        short8 aF[2], bF[4];
        for (int r = 0; r < 2; ++r)
            aF[r] = *(const short8*)&A_lds[w * 32 + r * 16 + lrow][kk];
        for (int c = 0; c < 4; ++c)
            bF[c] = *(const short8*)&B_lds[c * 16 + lrow][kk];
        for (int r = 0; r < 2; ++r)
            for (int c = 0; c < 4; ++c)
                acc[r][c] = __builtin_amdgcn_mfma_f32_16x16x32_bf16(
                    aF[r], bF[c], acc[r][c], 0, 0, 0);
    }

    // --- epilogue: write ze (fp32)
    const int rquad = lane >> 4;       // C/D: row = rquad*4 + reg, col = lane&15
    for (int r = 0; r < 2; ++r) {
        for (int c = 0; c < 4; ++c) {
            for (int reg = 0; reg < 4; ++reg) {
                const long row = e0 + w * 32 + r * 16 + rquad * 4 + reg;
                ze_out[row * IN_EDGE + c * 16 + lrow] = acc[r][c][reg];
            }
        }
    }
}

// ---------------------------------------------------------------------------
// CSR construction
// ---------------------------------------------------------------------------
#define SCAN_T 1024
#define SCAN_C 49

__global__ __launch_bounds__(SCAN_T) void k4_scan(
    const int* __restrict__ deg, int* __restrict__ off, int* __restrict__ cursor)
{
    __shared__ int part[SCAN_T];
    const int t = threadIdx.x;
    const int lo = t * SCAN_C;
    int hi = lo + SCAN_C; if (hi > N_NODES) hi = N_NODES;

    int s = 0;
    for (int i = lo; i < hi; ++i) s += deg[i];
    part[t] = s;
    __syncthreads();
    for (int d = 1; d < SCAN_T; d <<= 1) {
        int v = 0;
        if (t >= d) v = part[t - d];
        __syncthreads();
        if (t >= d) part[t] += v;
        __syncthreads();
    }
    int run = (t == 0) ? 0 : part[t - 1];
    for (int i = lo; i < hi; ++i) {
        off[i] = run; cursor[i] = run;
        run += deg[i];
    }
    if (t == SCAN_T - 1) off[N_NODES] = part[SCAN_T - 1];
}

__global__ void k5_fill(
    const int* __restrict__ src, const int* __restrict__ dst,
    const float* __restrict__ s_src, const float* __restrict__ s_dst,
    const float* __restrict__ s_e, int* __restrict__ cursor,
    int* __restrict__ csr_src, float* __restrict__ csr_e)
{
    const int i = blockIdx.x * blockDim.x + threadIdx.x;
    if (i >= N_EDGES) return;
    const int d = dst[i];
    const int s = src[i];
    const int pos = atomicAdd(&cursor[d], 1);
    csr_src[pos] = s;
    float e = s_src[s] + s_dst[d] + s_e[i];
    e = (e > 0.f) ? e : 0.2f * e;
    csr_e[pos] = e;
}

// ---------------------------------------------------------------------------
// K6: one wave per dst node: segment max -> exp-sum + weighted aggregation.
// ---------------------------------------------------------------------------
__global__ __launch_bounds__(256) void k6_aggregate(
    const int* __restrict__ off, const int* __restrict__ csr_src,
    const float* __restrict__ csr_e, const __hip_bfloat16* __restrict__ zb,
    float* __restrict__ h)
{
    const int wave = (int)((blockIdx.x * blockDim.x + threadIdx.x) >> 6);
    const int lane = threadIdx.x & 63;
    if (wave >= N_NODES) return;

    const int beg = off[wave];
    const int end = off[wave + 1];
    const int deg = end - beg;

    float2 acc = make_float2(0.f, 0.f);
    if (deg > 0) {
        float m = -INFINITY;
        for (int j = lane; j < deg; j += 64) m = fmaxf(m, csr_e[beg + j]);
        for (int o = 32; o > 0; o >>= 1) m = fmaxf(m, __shfl_xor(m, o, 64));

        float l = 0.f;
        for (int j = 0; j < deg; ++j) {
            const int s = csr_src[beg + j];
            const float w = __expf(csr_e[beg + j] - m);
            l += w;
            const __hip_bfloat162 zp =
                *(const __hip_bfloat162*)&zb[(size_t)s * OUT_DIM + lane * 2];
            const float2 zv = __bfloat1622float2(zp);
            acc.x += w * zv.x;
            acc.y += w * zv.y;
        }
        const float inv = 1.f / fmaxf(l, 1e-38f);
        acc.x *= inv; acc.y *= inv;
    }
    *(float2*)&h[(size_t)wave * OUT_DIM + lane * 2] = acc;
}

// ---------------------------------------------------------------------------
extern "C" void kernel_launch(void* const* d_in, const int* in_sizes, int n_in,
                              void* d_out, int out_size, void* d_ws, size_t ws_size,
                              hipStream_t stream)
{
    const float* fn  = (const float*)d_in[0];
    const float* fe  = (const float*)d_in[1];
    const int*   src = (const int*)d_in[2];
    const int*   dst = (const int*)d_in[3];
    const float* Wn  = (const float*)d_in[4];
    const float* We  = (const float*)d_in[5];
    const float* Wa  = (const float*)d_in[6];

    float* h_out  = (float*)d_out;                          // [50000,128]
    float* ze_out = h_out + (size_t)N_NODES * OUT_DIM;      // [800000,64]

    char* p = (char*)d_ws;
    auto alloc = [&](size_t bytes) -> char* {
        char* r = p;
        p += (bytes + 255) & ~(size_t)255;
        return r;
    };
    __hip_bfloat16* zb = (__hip_bfloat16*)alloc((size_t)N_NODES * OUT_DIM * 2);
    float* s_src   = (float*)alloc((size_t)N_NODES * 4);
    float* s_dst   = (float*)alloc((size_t)N_NODES * 4);
    float* s_e     = (float*)alloc((size_t)N_EDGES * 4);
    int*   deg     = (int*)alloc((size_t)N_NODES * 4);
    int*   off     = (int*)alloc((size_t)(N_NODES + 1) * 4);
    int*   cursor  = (int*)alloc((size_t)N_NODES * 4);
    int*   csr_src = (int*)alloc((size_t)N_EDGES * 4);
    float* csr_e   = (float*)alloc((size_t)N_EDGES * 4);
    float* v_e     = (float*)alloc((size_t)IN_EDGE * 4);

    hipMemsetAsync(deg, 0, (size_t)N_NODES * sizeof(int), stream);

    k0_ve<<<1, 64, 0, stream>>>(We, Wa, v_e);
    k1_node_gemm<<<(N_NODES + K1_MT - 1) / K1_MT, 256, 0, stream>>>(
        fn, Wn, Wa, zb, s_src, s_dst);
    k2_edge_gemm_mfma<<<N_EDGES / 128, 256, 0, stream>>>(
        fe, We, v_e, dst, deg, ze_out, s_e);
    k4_scan<<<1, SCAN_T, 0, stream>>>(deg, off, cursor);
    k5_fill<<<(N_EDGES + 255) / 256, 256, 0, stream>>>(
        src, dst, s_src, s_dst, s_e, cursor, csr_src, csr_e);
    k6_aggregate<<<(N_NODES + 3) / 4, 256, 0, stream>>>(
        off, csr_src, csr_e, zb, h_out);
}